// Round 11
// baseline (94.031 us; speedup 1.0000x reference)
//
#include <hip/hip_runtime.h>
#include <hip/hip_bf16.h>

// MLP_Interpolate: B=4, C=64, H=W=128, out 512x512, n_feat=64.
// Per INPUT pixel: f[j] = b1[j] + sum_c x*W1 (once, via bf16 MFMA); 16
// subpixels: h = relu(f + ay*W1[64,:] + ax*W1[65,:]); pred = h@W2 + b2.
//
// R10 (resubmit after broker timeout): R9 showed inter-block decorrelation
// buys only ~2us -> the exposed x-load latency + vmcnt(0)+barrier drain is
// per-block structural. Fix: 2-tile software pipeline per block
// (double-buffered fs): S1(T0); bar; S1(T1) loads issue; S2(T0) VALU burn
// hides them; bar; S2(T1). The wave hides its own latency instead of
// relying on the CU scheduler.

#define PLANE (512 * 512)
#define PITCH 68   // fs pitch: 0 conflicts measured R6

typedef __attribute__((ext_vector_type(8))) short  short8;   // 8 x bf16
typedef __attribute__((ext_vector_type(4))) float  f32x4;

__device__ __forceinline__ short bf16_of(float f) {
    __hip_bfloat16 h = __float2bfloat16(f);   // RNE
    return *reinterpret_cast<short*>(&h);
}

// stage 1: f = x @ W1[:64] + b1 for a 32-px tile, via bf16 MFMA.
// Fragment mapping verified R7 (absmax 0.0039): A row-major-K lane=(row
// l&15, k=32ks+8g+i, g=l>>4); B^T row-major-K lane=(col j, same k);
// C/D: col=l&15, row=4g+reg.
__device__ __forceinline__ void stage1(const float* __restrict__ xb,
                                       const float* __restrict__ W1,
                                       const float* __restrict__ b1,
                                       int w, int t, float (&fs)[32][PITCH]) {
    const int lane16 = t & 15;
    const int g      = t >> 4;
    const int mt     = w >> 1;
    const int nt0    = (w & 1) * 2;

    const float* xbase = xb + 16 * mt + lane16;
    short8 afrag[2];
    #pragma unroll
    for (int ks = 0; ks < 2; ++ks) {
        float tmp[8];
        #pragma unroll
        for (int i = 0; i < 8; ++i)
            tmp[i] = xbase[(size_t)(32 * ks + 8 * g + i) * 16384];
        #pragma unroll
        for (int i = 0; i < 8; ++i) afrag[ks][i] = bf16_of(tmp[i]);
    }

    #pragma unroll
    for (int ntp = 0; ntp < 2; ++ntp) {
        const int j = 16 * (nt0 + ntp) + lane16;
        short8 bfrag[2];
        #pragma unroll
        for (int ks = 0; ks < 2; ++ks) {
            float tmp[8];
            #pragma unroll
            for (int i = 0; i < 8; ++i)
                tmp[i] = W1[(32 * ks + 8 * g + i) * 64 + j];
            #pragma unroll
            for (int i = 0; i < 8; ++i) bfrag[ks][i] = bf16_of(tmp[i]);
        }

        const float b1j = b1[j];
        f32x4 acc = {b1j, b1j, b1j, b1j};
        acc = __builtin_amdgcn_mfma_f32_16x16x32_bf16(afrag[0], bfrag[0], acc, 0, 0, 0);
        acc = __builtin_amdgcn_mfma_f32_16x16x32_bf16(afrag[1], bfrag[1], acc, 0, 0, 0);

        #pragma unroll
        for (int r = 0; r < 4; ++r)
            fs[16 * mt + 4 * g + r][j] = acc[r];
    }
}

// stage 2: 16 subpixels for the tile. wave w = ry; lane -> (px = t&31,
// rx-half = t>>5), j-chunked (f[16] live window, no spill).
__device__ __forceinline__ void stage2(const float* __restrict__ W1,
                                       const float* __restrict__ W2,
                                       const float* __restrict__ b2,
                                       int w, int t, int k, int b, int l0t,
                                       const float (&fs)[32][PITCH],
                                       float* __restrict__ out) {
    const int p  = t & 31;
    const int rh = t >> 5;
    const int ry = w;
    const float ay  = (2 * ry - 3) * 0.25f;
    const float ax0 = (2 * (2 * rh)     - 3) * 0.25f;
    const float ax1 = (2 * (2 * rh + 1) - 3) * 0.25f;

    const float* Ay = W1 + 64 * 64;
    const float* Ax = W1 + 65 * 64;

    float p00 = b2[0], p10 = b2[1], p20 = b2[2];   // rx even
    float p01 = b2[0], p11 = b2[1], p21 = b2[2];   // rx odd

    #pragma unroll
    for (int q = 0; q < 4; ++q) {
        float f[16];
        #pragma unroll
        for (int u = 0; u < 4; ++u) {
            const float4 v = *(const float4*)&fs[p][16 * q + 4 * u];
            f[4*u] = v.x; f[4*u+1] = v.y; f[4*u+2] = v.z; f[4*u+3] = v.w;
        }
        #pragma unroll
        for (int i = 0; i < 16; ++i) {
            const int j = 16 * q + i;
            const float g2 = fmaf(ay, Ay[j], f[i]);
            const float h0 = fmaxf(fmaf(ax0, Ax[j], g2), 0.0f);
            const float h1 = fmaxf(fmaf(ax1, Ax[j], g2), 0.0f);
            const float w0 = W2[3*j + 0];
            const float w1 = W2[3*j + 1];
            const float w2 = W2[3*j + 2];
            p00 = fmaf(h0, w0, p00); p10 = fmaf(h0, w1, p10); p20 = fmaf(h0, w2, p20);
            p01 = fmaf(h1, w0, p01); p11 = fmaf(h1, w1, p11); p21 = fmaf(h1, w2, p21);
        }
    }

    const int oy  = 4 * k + ry;
    const int ox0 = (l0t + p) * 4 + 2 * rh;
    float* op = out + ((size_t)(b * 3) * 512 + oy) * 512 + ox0;
    float2 v0; v0.x = p00; v0.y = p01;
    float2 v1; v1.x = p10; v1.y = p11;
    float2 v2; v2.x = p20; v2.y = p21;
    *(float2*)(op)             = v0;
    *(float2*)(op +     PLANE) = v1;
    *(float2*)(op + 2 * PLANE) = v2;
}

__global__ __launch_bounds__(256, 4) void mlp_interp_kernel(
    const float* __restrict__ x,   // [4,64,128,128]
    const float* __restrict__ W1,  // [66,64]
    const float* __restrict__ b1,  // [64]
    const float* __restrict__ W2,  // [64,3]
    const float* __restrict__ b2,  // [3]
    float* __restrict__ out)       // [4,3,512,512]
{
    __shared__ float fs0[32][PITCH];   // tile 0   8.7 KiB
    __shared__ float fs1[32][PITCH];   // tile 1   8.7 KiB

    const int tid = threadIdx.x;
    const int w   = tid >> 6;          // wave 0..3
    const int t   = tid & 63;          // lane

    const int blk  = blockIdx.x;       // 0..1023
    const int lblk = blk & 1;          // half-strip of 64 px = 2 tiles
    const int k    = (blk >> 1) & 127; // input row
    const int b    = blk >> 8;         // batch
    const int l0   = lblk * 64;        // tile0 at l0, tile1 at l0+32

    const float* xb = x + (((size_t)(b * 64)) * 128 + k) * 128;

    // ---- pipeline: S1(T0); bar; S1(T1)+S2(T0); bar; S2(T1) ----
    stage1(xb + l0, W1, b1, w, t, fs0);
    __syncthreads();

    stage1(xb + l0 + 32, W1, b1, w, t, fs1);   // loads issue here...
    stage2(W1, W2, b2, w, t, k, b, l0, fs0, out);  // ...hide under this burn
    __syncthreads();

    stage2(W1, W2, b2, w, t, k, b, l0 + 32, fs1, out);
}

extern "C" void kernel_launch(void* const* d_in, const int* in_sizes, int n_in,
                              void* d_out, int out_size, void* d_ws, size_t ws_size,
                              hipStream_t stream) {
    const float* x  = (const float*)d_in[0];
    const float* W1 = (const float*)d_in[1];
    const float* b1 = (const float*)d_in[2];
    const float* W2 = (const float*)d_in[3];
    const float* b2 = (const float*)d_in[4];
    float* out = (float*)d_out;

    // blocks: b(4) * k(128) * half-strips(2) = 1024, 256 threads each
    mlp_interp_kernel<<<1024, 256, 0, stream>>>(x, W1, b1, W2, b2, out);
}

// Round 13
// 84.418 us; speedup vs baseline: 1.1139x; 1.1139x over previous
//
#include <hip/hip_runtime.h>
#include <hip/hip_bf16.h>

// MLP_Interpolate: B=4, C=64, H=W=128, out 512x512, n_feat=64.
// Per INPUT pixel: f[j] = b1[j] + sum_c x*W1 (once, via bf16 MFMA); 16
// subpixels: h = relu(f + ay*W1[64,:] + ax*W1[65,:]); pred = h@W2 + b2.
//
// R12 (resubmit after broker timeout): R10 proved hipcc won't interleave
// hand-sequenced phases (2-tile pipeline regressed 82->94us); R1-R9 show
// VALUBusy pinned ~25% at any occupancy => waves wait on the
// stage1->barrier->stage2 chain. Fix: BARRIER-FREE. One wave owns 16 px
// end-to-end (M=16 MFMA m-tile x 4 n-tiles); the fs transpose slice is
// wave-private LDS (lgkmcnt-ordered, no __syncthreads). 4096 independent
// wave-pipelines stagger freely, so the CU scheduler overlaps one wave's
// loads with another's stage-2 VALU.

#define PLANE (512 * 512)
#define PITCH 68   // fs row pitch (dwords): write 2-way (free), read broadcast

typedef __attribute__((ext_vector_type(8))) short  short8;   // 8 x bf16
typedef __attribute__((ext_vector_type(4))) float  f32x4;

__device__ __forceinline__ short bf16_of(float f) {
    __hip_bfloat16 h = __float2bfloat16(f);   // RNE
    return *reinterpret_cast<short*>(&h);
}

__global__ __launch_bounds__(128, 4) void mlp_interp_kernel(
    const float* __restrict__ x,   // [4,64,128,128]
    const float* __restrict__ W1,  // [66,64]
    const float* __restrict__ b1,  // [64]
    const float* __restrict__ W2,  // [64,3]
    const float* __restrict__ b2,  // [3]
    float* __restrict__ out)       // [4,3,512,512]
{
    __shared__ float fs[2][16][PITCH];   // per-wave private slice, 8.7 KiB

    const int tid = threadIdx.x;
    const int w   = tid >> 6;            // wave 0..1
    const int t   = tid & 63;

    const int blk   = blockIdx.x;        // 0..2047
    const int strip = blk & 3;           // 32-px strip
    const int k     = (blk >> 2) & 127;  // input row
    const int b     = blk >> 9;          // batch
    const int l0    = strip * 32 + w * 16;   // this wave's 16 pixels

    const int lane16 = t & 15;
    const int g      = t >> 4;

    // ======== stage 1 (wave-local): f[16px][64j] = x @ W1[:64] + b1 =======
    // MFMA mapping verified R7 (absmax 0.0039): A row-major-K lane=(row
    // l&15, k=32ks+8g+i); B^T lane=(col j, same k); C/D col=l&15, row=4g+r.
    {
        const float* xbase = x + (((size_t)(b * 64)) * 128 + k) * 128 + l0 + lane16;
        short8 afrag[2];
        #pragma unroll
        for (int ks = 0; ks < 2; ++ks) {
            float tmp[8];
            #pragma unroll
            for (int i = 0; i < 8; ++i)
                tmp[i] = xbase[(size_t)(32 * ks + 8 * g + i) * 16384];
            #pragma unroll
            for (int i = 0; i < 8; ++i) afrag[ks][i] = bf16_of(tmp[i]);
        }

        #pragma unroll
        for (int nt = 0; nt < 4; ++nt) {
            const int j = 16 * nt + lane16;
            short8 bfrag[2];
            #pragma unroll
            for (int ks = 0; ks < 2; ++ks) {
                float tmp[8];
                #pragma unroll
                for (int i = 0; i < 8; ++i)
                    tmp[i] = W1[(32 * ks + 8 * g + i) * 64 + j];
                #pragma unroll
                for (int i = 0; i < 8; ++i) bfrag[ks][i] = bf16_of(tmp[i]);
            }

            const float b1j = b1[j];
            f32x4 acc = {b1j, b1j, b1j, b1j};
            acc = __builtin_amdgcn_mfma_f32_16x16x32_bf16(afrag[0], bfrag[0], acc, 0, 0, 0);
            acc = __builtin_amdgcn_mfma_f32_16x16x32_bf16(afrag[1], bfrag[1], acc, 0, 0, 0);

            #pragma unroll
            for (int r = 0; r < 4; ++r)
                fs[w][4 * g + r][j] = acc[r];   // wave-private: no barrier
        }
    }
    // NO __syncthreads(): same wave wrote and reads its fs slice;
    // LDS ops within a wave are ordered via lgkmcnt.

    // ======== stage 2: lane = (px = lane16, ry = g); all 4 rx ============
    {
        const int px = lane16;
        const int ry = g;
        const float ay = (2 * ry - 3) * 0.25f;
        const float ax0 = -0.75f, ax1 = -0.25f, ax2 = 0.25f, ax3 = 0.75f;

        const float* Ay = W1 + 64 * 64;
        const float* Ax = W1 + 65 * 64;

        // p[rx][ch], fully unrolled -> registers (12 acc)
        float p0c0 = b2[0], p0c1 = b2[1], p0c2 = b2[2];
        float p1c0 = b2[0], p1c1 = b2[1], p1c2 = b2[2];
        float p2c0 = b2[0], p2c1 = b2[1], p2c2 = b2[2];
        float p3c0 = b2[0], p3c1 = b2[1], p3c2 = b2[2];

        #pragma unroll
        for (int q = 0; q < 4; ++q) {
            float f[16];
            #pragma unroll
            for (int u = 0; u < 4; ++u) {
                const float4 v = *(const float4*)&fs[w][px][16 * q + 4 * u];
                f[4*u] = v.x; f[4*u+1] = v.y; f[4*u+2] = v.z; f[4*u+3] = v.w;
            }
            #pragma unroll
            for (int i = 0; i < 16; ++i) {
                const int j = 16 * q + i;
                const float g2 = fmaf(ay, Ay[j], f[i]);
                const float axj = Ax[j];
                const float h0 = fmaxf(fmaf(ax0, axj, g2), 0.0f);
                const float h1 = fmaxf(fmaf(ax1, axj, g2), 0.0f);
                const float h2 = fmaxf(fmaf(ax2, axj, g2), 0.0f);
                const float h3 = fmaxf(fmaf(ax3, axj, g2), 0.0f);
                const float w0 = W2[3*j + 0];
                const float w1 = W2[3*j + 1];
                const float w2 = W2[3*j + 2];
                p0c0 = fmaf(h0, w0, p0c0); p0c1 = fmaf(h0, w1, p0c1); p0c2 = fmaf(h0, w2, p0c2);
                p1c0 = fmaf(h1, w0, p1c0); p1c1 = fmaf(h1, w1, p1c1); p1c2 = fmaf(h1, w2, p1c2);
                p2c0 = fmaf(h2, w0, p2c0); p2c1 = fmaf(h2, w1, p2c1); p2c2 = fmaf(h2, w2, p2c2);
                p3c0 = fmaf(h3, w0, p3c0); p3c1 = fmaf(h3, w1, p3c1); p3c2 = fmaf(h3, w2, p3c2);
            }
        }

        // lane stores float4 per channel: 16 lanes x 16B contiguous
        const int oy  = 4 * k + ry;
        const int ox0 = (l0 + px) * 4;
        float* op = out + ((size_t)(b * 3) * 512 + oy) * 512 + ox0;
        float4 v0; v0.x = p0c0; v0.y = p1c0; v0.z = p2c0; v0.w = p3c0;
        float4 v1; v1.x = p0c1; v1.y = p1c1; v1.z = p2c1; v1.w = p3c1;
        float4 v2; v2.x = p0c2; v2.y = p1c2; v2.z = p2c2; v2.w = p3c2;
        *(float4*)(op)             = v0;
        *(float4*)(op +     PLANE) = v1;
        *(float4*)(op + 2 * PLANE) = v2;
    }
}

extern "C" void kernel_launch(void* const* d_in, const int* in_sizes, int n_in,
                              void* d_out, int out_size, void* d_ws, size_t ws_size,
                              hipStream_t stream) {
    const float* x  = (const float*)d_in[0];
    const float* W1 = (const float*)d_in[1];
    const float* b1 = (const float*)d_in[2];
    const float* W2 = (const float*)d_in[3];
    const float* b2 = (const float*)d_in[4];
    float* out = (float*)d_out;

    // blocks: b(4) * k(128) * strips(4) = 2048, 128 threads (2 waves) each
    mlp_interp_kernel<<<2048, 128, 0, stream>>>(x, W1, b1, W2, b2, out);
}

// Round 14
// 82.785 us; speedup vs baseline: 1.1358x; 1.0197x over previous
//
#include <hip/hip_runtime.h>
#include <hip/hip_bf16.h>

// MLP_Interpolate: B=4, C=64, H=W=128, out 512x512, n_feat=64.
// Per INPUT pixel: f[j] = b1[j] + sum_c x*W1 (once, via bf16 MFMA); 16
// subpixels: h = relu(f + ay*W1[64,:] + ax*W1[65,:]); pred = h@W2 + b2.
//
// R14: R7/R9/R13 all land ~18-20us despite radically different schedules;
// per-wave issue is ~4-5k cyc vs ~45k cyc lifetime => stall is a SHARED
// per-CU resource, not per-wave latency. Two suspects attacked here:
//  (1) W1 read as 128 scattered 4-line gather instrs per block (every wave
//      streams all 16KB of W1 through the vector pipe). Fix: cooperative
//      once-per-block W1 -> LDS bf16 TRANSPOSED [j][c]; B-frags become
//      8 ds_read_b128 per wave (2-way bank max at pitch 72).
//  (2) ~20KB fully-unrolled straight-line code streaming through the
//      per-CU instruction fetch every wave (VALUBusy pinned 23-27% at any
//      occupancy). Fix: re-roll stage 2 (4x j-chunk loop) -> ~6KB code.
// FP order unchanged everywhere => absmax stays 0.00390625 exactly.

#define PLANE (512 * 512)
#define FPITCH 68   // fs pitch (dwords): reads 2-way max (free), 0 measured
#define WPITCH 72   // W1T pitch (bf16 elems) = 144B/row: b128 reads 2-way max

typedef __attribute__((ext_vector_type(8))) short  short8;   // 8 x bf16
typedef __attribute__((ext_vector_type(4))) float  f32x4;

__device__ __forceinline__ short bf16_of(float f) {
    __hip_bfloat16 h = __float2bfloat16(f);   // RNE
    return *reinterpret_cast<short*>(&h);
}

__global__ __launch_bounds__(128, 4) void mlp_interp_kernel(
    const float* __restrict__ x,   // [4,64,128,128]
    const float* __restrict__ W1,  // [66,64]
    const float* __restrict__ b1,  // [64]
    const float* __restrict__ W2,  // [64,3]
    const float* __restrict__ b2,  // [3]
    float* __restrict__ out)       // [4,3,512,512]
{
    __shared__ __align__(16) short W1T[64][WPITCH];  // [j][c] bf16, 9.2 KiB
    __shared__ float fs[2][16][FPITCH];              // per-wave slice, 8.7 KiB

    const int tid = threadIdx.x;
    const int w   = tid >> 6;            // wave 0..1
    const int t   = tid & 63;

    const int blk   = blockIdx.x;        // 0..2047
    const int strip = blk & 3;           // 32-px strip
    const int k     = (blk >> 2) & 127;  // input row
    const int b     = blk >> 9;          // batch
    const int l0    = strip * 32 + w * 16;   // this wave's 16 pixels

    const int lane16 = t & 15;
    const int g      = t >> 4;

    // ---- cooperative W1[:64] -> LDS bf16 transpose, once per block ----
    // thread t: j-quad jq = t&15, c-pair base cp = t>>4; 4 iters cover all
    // 32 c-pairs. Coalesced float4 global loads; packed b32 LDS writes.
    {
        const int jq = tid & 15;
        const int cp = tid >> 4;          // 0..7
        #pragma unroll
        for (int it = 0; it < 4; ++it) {
            const int c0 = 2 * (cp + 8 * it);
            const float4 v0 = *(const float4*)&W1[c0 * 64 + 4 * jq];
            const float4 v1 = *(const float4*)&W1[(c0 + 1) * 64 + 4 * jq];
            const float* p0 = (const float*)&v0;
            const float* p1 = (const float*)&v1;
            #pragma unroll
            for (int u = 0; u < 4; ++u) {
                const unsigned lo = (unsigned short)bf16_of(p0[u]);
                const unsigned hi = (unsigned short)bf16_of(p1[u]);
                *(unsigned*)&W1T[4 * jq + u][c0] = lo | (hi << 16);
            }
        }
    }
    __syncthreads();

    // ======== stage 1 (wave-local): f[16px][64j] = x @ W1[:64] + b1 =======
    // MFMA mapping verified R7 (absmax 0.0039): A row-major-K lane=(row
    // l&15, k=32ks+8g+i); B^T lane=(col j, k contiguous); C/D col=l&15,
    // row=4g+r. B-frag now: one ds_read_b128 per (nt,ks) from W1T[j][c].
    {
        const float* xbase = x + (((size_t)(b * 64)) * 128 + k) * 128 + l0 + lane16;
        short8 afrag[2];
        #pragma unroll
        for (int ks = 0; ks < 2; ++ks) {
            float tmp[8];
            #pragma unroll
            for (int i = 0; i < 8; ++i)
                tmp[i] = xbase[(size_t)(32 * ks + 8 * g + i) * 16384];
            #pragma unroll
            for (int i = 0; i < 8; ++i) afrag[ks][i] = bf16_of(tmp[i]);
        }

        #pragma unroll
        for (int nt = 0; nt < 4; ++nt) {
            const int j = 16 * nt + lane16;
            short8 bfrag[2];
            #pragma unroll
            for (int ks = 0; ks < 2; ++ks)
                bfrag[ks] = *(const short8*)&W1T[j][32 * ks + 8 * g];

            const float b1j = b1[j];
            f32x4 acc = {b1j, b1j, b1j, b1j};
            acc = __builtin_amdgcn_mfma_f32_16x16x32_bf16(afrag[0], bfrag[0], acc, 0, 0, 0);
            acc = __builtin_amdgcn_mfma_f32_16x16x32_bf16(afrag[1], bfrag[1], acc, 0, 0, 0);

            #pragma unroll
            for (int r = 0; r < 4; ++r)
                fs[w][4 * g + r][j] = acc[r];   // wave-private: no barrier
        }
    }
    // NO __syncthreads(): same wave wrote and reads its fs slice (lgkmcnt).

    // ======== stage 2: lane = (px = lane16, ry = g); all 4 rx ============
    // Rolled over q (4 chunks of 16 j) to shrink i-fetch footprint; inner
    // body fully unrolled. FP order identical to R12/R13.
    {
        const int px = lane16;
        const int ry = g;
        const float ay = (2 * ry - 3) * 0.25f;
        const float ax0 = -0.75f, ax1 = -0.25f, ax2 = 0.25f, ax3 = 0.75f;

        const float* Ay = W1 + 64 * 64;
        const float* Ax = W1 + 65 * 64;

        float p0c0 = b2[0], p0c1 = b2[1], p0c2 = b2[2];
        float p1c0 = b2[0], p1c1 = b2[1], p1c2 = b2[2];
        float p2c0 = b2[0], p2c1 = b2[1], p2c2 = b2[2];
        float p3c0 = b2[0], p3c1 = b2[1], p3c2 = b2[2];

        #pragma unroll 1
        for (int q = 0; q < 4; ++q) {
            float f[16];
            #pragma unroll
            for (int u = 0; u < 4; ++u) {
                const float4 v = *(const float4*)&fs[w][px][16 * q + 4 * u];
                f[4*u] = v.x; f[4*u+1] = v.y; f[4*u+2] = v.z; f[4*u+3] = v.w;
            }
            #pragma unroll
            for (int i = 0; i < 16; ++i) {
                const int j = 16 * q + i;
                const float g2 = fmaf(ay, Ay[j], f[i]);
                const float axj = Ax[j];
                const float h0 = fmaxf(fmaf(ax0, axj, g2), 0.0f);
                const float h1 = fmaxf(fmaf(ax1, axj, g2), 0.0f);
                const float h2 = fmaxf(fmaf(ax2, axj, g2), 0.0f);
                const float h3 = fmaxf(fmaf(ax3, axj, g2), 0.0f);
                const float w0 = W2[3*j + 0];
                const float w1 = W2[3*j + 1];
                const float w2 = W2[3*j + 2];
                p0c0 = fmaf(h0, w0, p0c0); p0c1 = fmaf(h0, w1, p0c1); p0c2 = fmaf(h0, w2, p0c2);
                p1c0 = fmaf(h1, w0, p1c0); p1c1 = fmaf(h1, w1, p1c1); p1c2 = fmaf(h1, w2, p1c2);
                p2c0 = fmaf(h2, w0, p2c0); p2c1 = fmaf(h2, w1, p2c1); p2c2 = fmaf(h2, w2, p2c2);
                p3c0 = fmaf(h3, w0, p3c0); p3c1 = fmaf(h3, w1, p3c1); p3c2 = fmaf(h3, w2, p3c2);
            }
        }

        // lane stores float4 per channel: 16 lanes x 16B contiguous
        const int oy  = 4 * k + ry;
        const int ox0 = (l0 + px) * 4;
        float* op = out + ((size_t)(b * 3) * 512 + oy) * 512 + ox0;
        float4 v0; v0.x = p0c0; v0.y = p1c0; v0.z = p2c0; v0.w = p3c0;
        float4 v1; v1.x = p0c1; v1.y = p1c1; v1.z = p2c1; v1.w = p3c1;
        float4 v2; v2.x = p0c2; v2.y = p1c2; v2.z = p2c2; v2.w = p3c2;
        *(float4*)(op)             = v0;
        *(float4*)(op +     PLANE) = v1;
        *(float4*)(op + 2 * PLANE) = v2;
    }
}

extern "C" void kernel_launch(void* const* d_in, const int* in_sizes, int n_in,
                              void* d_out, int out_size, void* d_ws, size_t ws_size,
                              hipStream_t stream) {
    const float* x  = (const float*)d_in[0];
    const float* W1 = (const float*)d_in[1];
    const float* b1 = (const float*)d_in[2];
    const float* W2 = (const float*)d_in[3];
    const float* b2 = (const float*)d_in[4];
    float* out = (float*)d_out;

    // blocks: b(4) * k(128) * strips(4) = 2048, 128 threads (2 waves) each
    mlp_interp_kernel<<<2048, 128, 0, stream>>>(x, W1, b1, W2, b2, out);
}